// Round 14
// baseline (92.236 us; speedup 1.0000x reference)
//
#include <hip/hip_runtime.h>
#include <math.h>

typedef __attribute__((ext_vector_type(8))) short short8;
typedef __attribute__((ext_vector_type(4))) short short4v;
typedef __attribute__((ext_vector_type(4))) float f32x4;
typedef __attribute__((ext_vector_type(2))) float f32x2;

#define DEV static __device__ __forceinline__

DEV unsigned short f2b(float f){            // fp32 -> bf16 (RNE)
  union{float f; unsigned u;} x; x.f = f;
  unsigned r = (x.u + 0x7fffu + ((x.u>>16)&1u))>>16;
  return (unsigned short)r;
}
DEV float b2f(unsigned short u){            // bf16 -> fp32
  union{unsigned u; float f;} x; x.u = ((unsigned)u)<<16; return x.f;
}

#define MFMA(a,b,c) __builtin_amdgcn_mfma_f32_16x16x32_bf16((a),(b),(c),0,0,0)

// ---------------------------------------------------------------------------
// Weight-prep: ids [0,94208) -> bf16 B-frag order (LN-affine folded);
// [94208,98816): qkv bias folds, 16 lanes per element (shfl tree reduce);
// [98816,99840): mlp b1 fold, 16 lanes per element.
// ---------------------------------------------------------------------------
DEV void prep_one(int id,
    const float* inW, const float* Wq, const float* Wk, const float* Wv,
    const float* m1, const float* m2,
    const float* p1, const float* p2, const float* p3, const float* p4,
    const float* mss, const float* mls, const float* msb,
    const float* bq, const float* bk, const float* bv,
    const float* mlb, const float* mb1,
    unsigned short* wsw, float* qkvb, float* mlpb1)
{
  if(id < 94208){
    const float* src; int NT, base; int harg = -1, w1flag = 0;
    if      (id < 49152){ src=inW; NT=4; base=0; }
    else if (id < 67584){ int r=id-49152; int slab=r>>11; int h=slab/3, m=slab-h*3;
                          src=(m==0?Wq:(m==1?Wk:Wv))+h*2048; NT=2; base=49152+slab*2048; harg=h; }
    else if (id < 73728){ src=m1; NT=4; base=67584; }
    else if (id < 77824){ src=m2; NT=4; base=73728; }
    else if (id < 81920){ src=p1; NT=4; base=77824; w1flag=1; }
    else if (id < 86016){ src=p2; NT=4; base=81920; }
    else if (id < 90112){ src=p3; NT=4; base=86016; }
    else                { src=p4; NT=4; base=90112; }
    int o = id - base;
    int j = o&7, l = (o>>3)&63, rest = o>>9;
    int nt = rest % NT, kc = rest / NT;
    int k = kc*32 + ((l>>4)<<3) + j;
    int n = nt*16 + (l&15);
    float scale = 1.f;
    if(harg >= 0) scale = mss[harg*64 + k];
    if(w1flag)    scale = mls[k];
    wsw[id] = f2b(src[k*(NT*16) + n] * scale);
  } else if(id < 98816){
    int o16 = id - 94208;                   // 4608 = 288 elems * 16 lanes
    int elem = o16 >> 4, part = o16 & 15;
    int h = elem/96, m = (elem - h*96)/32, e = elem&31;
    const float* W  = (m==0?Wq:(m==1?Wk:Wv)) + h*2048;
    const float* bb = (m==0?bq:(m==1?bk:bv));
    float s = 0.f;
#pragma unroll
    for(int u=0; u<4; ++u){
      int l = part*4 + u;
      s += msb[h*64+l]*W[l*32+e];
    }
    s += __shfl_xor(s,1); s += __shfl_xor(s,2);
    s += __shfl_xor(s,4); s += __shfl_xor(s,8);
    if(part==0) qkvb[elem] = s + bb[h*32+e];
  } else if(id < 99840){
    int o16 = id - 98816;                   // 1024 = 64 elems * 16 lanes
    int n = o16 >> 4, part = o16 & 15;
    float s = 0.f;
#pragma unroll
    for(int u=0; u<4; ++u){
      int l = part*4 + u;
      s += mlb[l]*p1[l*64+n];
    }
    s += __shfl_xor(s,1); s += __shfl_xor(s,2);
    s += __shfl_xor(s,4); s += __shfl_xor(s,8);
    if(part==0) mlpb1[n] = s + mb1[n];
  }
}

// kprep: in_W frags (needed by k1). 192 blocks.
__global__ __launch_bounds__(256) void kprep(
    const float* __restrict__ inW, unsigned short* __restrict__ wsw)
{
  int id = blockIdx.x*256 + threadIdx.x;   // < 49152
  int o = id;
  int j = o&7, l = (o>>3)&63, rest = o>>9;
  int nt = rest & 3, kc = rest >> 2;
  int k = kc*32 + ((l>>4)<<3) + j;
  int n = nt*16 + (l&15);
  wsw[id] = f2b(inW[k*64 + n]);
}

// ---------------------------------------------------------------------------
// k1: blocks [0,198): weight prep. blocks [198,4294): patchify + LN(768) +
// GEMM(768->64) + bias + LN(64) -> xskip (bf16) + z (bf16, kA A-frag order).
// LDS-overlay version: Cbuf and wstat alias Tf (phase-disjoint, barriers
// inserted) -> 24.6 KB LDS -> 6 blocks/CU (was 5).
// ---------------------------------------------------------------------------
__global__ __launch_bounds__(256) void k1_patch(
    const float* __restrict__ x,
    const float* __restrict__ ln1s, const float* __restrict__ ln1b,
    unsigned short* __restrict__ wsw, const float* __restrict__ inb,
    const float* __restrict__ ln2s, const float* __restrict__ ln2b,
    unsigned short* __restrict__ xskip, unsigned short* __restrict__ zf,
    const float* __restrict__ inW,
    const float* __restrict__ Wq, const float* __restrict__ Wk,
    const float* __restrict__ Wv,
    const float* __restrict__ m1, const float* __restrict__ m2,
    const float* __restrict__ p1, const float* __restrict__ p2,
    const float* __restrict__ p3, const float* __restrict__ p4,
    const float* __restrict__ mss, const float* __restrict__ mls,
    const float* __restrict__ msb,
    const float* __restrict__ bq, const float* __restrict__ bk,
    const float* __restrict__ bv,
    const float* __restrict__ mlb, const float* __restrict__ mb1,
    float* __restrict__ qkvb, float* __restrict__ mlpb1)
{
  const int tid = threadIdx.x;
  const int bp = blockIdx.x;
  if(bp < 198){   // weight-prep first
    int id = 49152 + bp*256 + tid;
    if(id < 99840)
      prep_one(id, inW, Wq, Wk, Wv, m1, m2, p1, p2, p3, p4,
               mss, mls, msb, bq, bk, bv, mlb, mb1, wsw, qkvb, mlpb1);
    return;
  }
  const int bp2 = bp - 198;
  __shared__ unsigned short Tf[24*64*8];               // 24,576 B (only LDS)
  float (*wstat)[16][2] = (float(*)[16][2])Tf;         // alias, phase 2 only
  float (*Cbuf)[68]     = (float(*)[68])Tf;            // alias, phase 5 only
  const int lane = tid & 63, wv = tid >> 6;
  const int b = bp2 >> 4, p0 = bp2 & 15;
  const int a = lane & 3;

  const float* xb = x + (size_t)b * (3*256*256);
  f32x4 rv[12];
  float sum[4] = {0.f,0.f,0.f,0.f}, ssq[4] = {0.f,0.f,0.f,0.f};
#pragma unroll
  for(int it=0; it<12; ++it){
    int rr = it*4 + wv;            // row 0..47 (wave-striped)
    int c = rr >> 4, i = rr & 15;
    rv[it] = *(const f32x4*)&xb[(size_t)(c*256 + i*16 + p0)*256 + lane*4];
#pragma unroll
    for(int u=0; u<4; ++u){ float v = rv[it][u]; sum[u] += v; ssq[u] += v*v; }
  }
#pragma unroll
  for(int u=0; u<4; ++u){
    sum[u] += __shfl_xor(sum[u],4);  ssq[u] += __shfl_xor(ssq[u],4);
    sum[u] += __shfl_xor(sum[u],8);  ssq[u] += __shfl_xor(ssq[u],8);
    sum[u] += __shfl_xor(sum[u],16); ssq[u] += __shfl_xor(ssq[u],16);
    sum[u] += __shfl_xor(sum[u],32); ssq[u] += __shfl_xor(ssq[u],32);
  }
  if(lane < 4){
#pragma unroll
    for(int u=0; u<4; ++u){
      wstat[wv][lane*4+u][0] = sum[u];
      wstat[wv][lane*4+u][1] = ssq[u];
    }
  }
  __syncthreads();
  float mean[4], rstd[4];
#pragma unroll
  for(int u=0; u<4; ++u){
    int pv = a*4 + u;
    float ts = wstat[0][pv][0]+wstat[1][pv][0]+wstat[2][pv][0]+wstat[3][pv][0];
    float tq = wstat[0][pv][1]+wstat[1][pv][1]+wstat[2][pv][1]+wstat[3][pv][1];
    mean[u] = ts * (1.f/768.f);
    rstd[u] = rsqrtf(tq*(1.f/768.f) - mean[u]*mean[u] + 1e-5f);
  }
  __syncthreads();   // wstat reads done before Tf overwrite (overlay)
#pragma unroll
  for(int it=0; it<12; ++it){
    int rr = it*4 + wv;
    int c = rr >> 4, i = rr & 15, j = lane >> 2;
    int d = c*256 + i*16 + j;
    float ls = ln1s[d], lb = ln1b[d];
    int tb = ((d>>5)*64 + ((d&31)>>3)*16)*8 + (d&7);
#pragma unroll
    for(int u=0; u<4; ++u){
      float xv = (rv[it][u]-mean[u])*rstd[u]*ls + lb;
      Tf[ tb + (a*4+u)*8 ] = f2b(xv);
    }
  }
  __syncthreads();

  f32x4 acc = {0.f,0.f,0.f,0.f};
  const short8* wf = (const short8*)wsw;
#pragma unroll
  for(int kc=0; kc<24; ++kc){
    short8 aa = *(const short8*)&Tf[(kc*64 + lane)*8];
    short8 bb = wf[(kc*4 + wv)*64 + lane];
    acc = MFMA(aa, bb, acc);
  }
  const int c15 = lane & 15, rg = lane >> 4;
  float bias = inb[wv*16 + c15];
  __syncthreads();   // all Tf reads (MFMA) done before Cbuf overwrite (overlay)
#pragma unroll
  for(int r=0; r<4; ++r) Cbuf[rg*4+r][wv*16+c15] = acc[r] + bias;
  __syncthreads();

  {
    int row = tid >> 4, cq = (tid & 15) * 4;
    float v0=Cbuf[row][cq+0], v1=Cbuf[row][cq+1], v2=Cbuf[row][cq+2], v3=Cbuf[row][cq+3];
    float s = v0+v1+v2+v3;
    float q = v0*v0+v1*v1+v2*v2+v3*v3;
    s += __shfl_xor(s,1); s += __shfl_xor(s,2); s += __shfl_xor(s,4); s += __shfl_xor(s,8);
    q += __shfl_xor(q,1); q += __shfl_xor(q,2); q += __shfl_xor(q,4); q += __shfl_xor(q,8);
    float m2  = s*(1.f/64.f);
    float rs2 = rsqrtf(q*(1.f/64.f) - m2*m2 + 1e-5f);
    f32x4 o;
    o[0] = (v0-m2)*rs2*ln2s[cq+0] + ln2b[cq+0];
    o[1] = (v1-m2)*rs2*ln2s[cq+1] + ln2b[cq+1];
    o[2] = (v2-m2)*rs2*ln2s[cq+2] + ln2b[cq+2];
    o[3] = (v3-m2)*rs2*ln2s[cq+3] + ln2b[cq+3];
    int grow = b*256 + p0*16 + row;
    short4v xb4;
    xb4[0]=(short)f2b(o[0]); xb4[1]=(short)f2b(o[1]);
    xb4[2]=(short)f2b(o[2]); xb4[3]=(short)f2b(o[3]);
    *(short4v*)&xskip[ (size_t)grow*64 + cq ] = xb4;
    // second LN stats (all 16 lanes get totals via butterfly)
    float s2 = o[0]+o[1]+o[2]+o[3];
    float q2 = o[0]*o[0]+o[1]*o[1]+o[2]*o[2]+o[3]*o[3];
    s2 += __shfl_xor(s2,1); s2 += __shfl_xor(s2,2); s2 += __shfl_xor(s2,4); s2 += __shfl_xor(s2,8);
    q2 += __shfl_xor(q2,1); q2 += __shfl_xor(q2,2); q2 += __shfl_xor(q2,4); q2 += __shfl_xor(q2,8);
    float mm  = s2*(1.f/64.f);
    float rr2 = rsqrtf(q2*(1.f/64.f) - mm*mm + 1e-5f);
    short4v zz;
    zz[0] = (short)f2b((o[0]-mm)*rr2);
    zz[1] = (short)f2b((o[1]-mm)*rr2);
    zz[2] = (short)f2b((o[2]-mm)*rr2);
    zz[3] = (short)f2b((o[3]-mm)*rr2);
    int fi = (p0*2 + (cq>>5))*512 + ((cq&31)>>3)*128 + row*8 + (cq&7);
    *(short4v*)&zf[ (size_t)b*16384 + fi ] = zz;
  }
}

// ---------------------------------------------------------------------------
// kA: fused attention per (b,h). A-frags (z) loaded directly from global
// (coalesced 16B/lane); QKV -> Q regs / K,V LDS; QK^T, in-register softmax
// (normalization DEFERRED to output), P staged per-kc via per-wave scratch,
// PV; O staged through scratch -> contiguous short8 catg stores.
// ---------------------------------------------------------------------------
__global__ __launch_bounds__(256) void kA_attn(
    const unsigned short* __restrict__ zf,
    const unsigned short* __restrict__ wsw, const float* __restrict__ qkvb,
    unsigned short* __restrict__ catg)
{
  __shared__ unsigned short Kf[8192];      // 16 KB
  __shared__ unsigned short Vf[8192];      // 16 KB
  __shared__ unsigned short scr[4][1024];  //  8 KB (per-wave 2 KB)
  const int tid = threadIdx.x, lane = tid&63, wv = tid>>6;
  const int c15 = lane&15, rg = lane>>4;
  const int id = blockIdx.x, b = id/3, h = id - b*3;
  const short8* zg = (const short8*)(zf + (size_t)b*16384);
  const short8* wf = ((const short8*)(wsw + 49152)) + h*3*256;
  unsigned short* sw = scr[wv];
  float be[6];
#pragma unroll
  for(int i=0;i<6;++i) be[i] = qkvb[(h*3 + (i>>1))*32 + (i&1)*16 + c15];

  short8 aq[4];                            // Q A-frags, one per st
#pragma unroll
  for(int si=0; si<4; ++si){
    const int st = wv + si*4;
    short8 a0 = zg[(st*2+0)*64 + lane];
    short8 a1 = zg[(st*2+1)*64 + lane];
#pragma unroll
    for(int mat=0; mat<3; ++mat){
#pragma unroll
      for(int et=0; et<2; ++et){
        f32x4 acc = {0.f,0.f,0.f,0.f};
        acc = MFMA(a0, wf[mat*256 + et*64 + lane], acc);
        acc = MFMA(a1, wf[mat*256 + (2+et)*64 + lane], acc);
        float bias = be[mat*2+et];
#pragma unroll
        for(int r=0;r<4;++r){
          unsigned short val = f2b(acc[r] + bias);
          int s15 = rg*4 + r;
          if(mat==0){
            sw[ ((et*2 + (c15>>3))*16 + s15)*8 + (c15&7) ] = val;
          } else if(mat==1){
            Kf[ (st*64 + (et*2 + (c15>>3))*16 + s15)*8 + (c15&7) ] = val;
          } else {
            int s = st*16 + s15;
            Vf[ (((s>>5)*2 + et)*64 + ((s&31)>>3)*16 + c15)*8 + (s&7) ] = val;
          }
        }
      }
      if(mat==0) aq[si] = ((const short8*)sw)[lane];   // wave-local readback
    }
  }
  __syncthreads();

  const f32x4 z4 = {0.f,0.f,0.f,0.f};
#pragma unroll
  for(int si=0; si<4; ++si){
    const int st = wv + si*4;
    f32x4 sc[16];
#pragma unroll
    for(int tt=0; tt<16; ++tt) sc[tt] = MFMA(aq[si], ((const short8*)Kf)[tt*64 + lane], z4);
    float mx[4], sm[4];
#pragma unroll
    for(int r=0; r<4; ++r){
      float m = sc[0][r];
#pragma unroll
      for(int tt=1; tt<16; ++tt) m = fmaxf(m, sc[tt][r]);
      m = fmaxf(m, __shfl_xor(m,1)); m = fmaxf(m, __shfl_xor(m,2));
      m = fmaxf(m, __shfl_xor(m,4)); m = fmaxf(m, __shfl_xor(m,8));
      mx[r] = m; sm[r] = 0.f;
    }
#pragma unroll
    for(int tt=0; tt<16; ++tt)
#pragma unroll
      for(int r=0; r<4; ++r){
        float e = __expf(sc[tt][r] - mx[r]);
        sc[tt][r] = e; sm[r] += e;
      }
#pragma unroll
    for(int r=0; r<4; ++r){
      float s = sm[r];
      s += __shfl_xor(s,1); s += __shfl_xor(s,2); s += __shfl_xor(s,4); s += __shfl_xor(s,8);
      sm[r] = 1.f / s;
    }
    f32x4 o0 = z4, o1 = z4;
#pragma unroll
    for(int kc=0; kc<8; ++kc){
#pragma unroll
      for(int t2=0; t2<2; ++t2){
        int tt = kc*2 + t2;
        int tbr = t2*16 + c15;
#pragma unroll
        for(int r=0; r<4; ++r)
          sw[ (((tbr>>3)*16 + rg*4 + r)<<3) + (tbr&7) ] = f2b(sc[tt][r]);  // raw exp
      }
      short8 pa = ((const short8*)sw)[lane];
      o0 = MFMA(pa, ((const short8*)Vf)[(kc*2+0)*64 + lane], o0);
      o1 = MFMA(pa, ((const short8*)Vf)[(kc*2+1)*64 + lane], o1);
    }
    {  // deferred normalization + stage via scratch -> contiguous stores
      int fo = (c15>>3)*128 + (c15&7);
#pragma unroll
      for(int r=0; r<4; ++r){
        int q8 = (rg*4 + r)*8;
        sw[ fo + q8 ]       = f2b(o0[r]*sm[r]);   // et0 tile -> sw[0..255]
        sw[ 256 + fo + q8 ] = f2b(o1[r]*sm[r]);   // et1 tile -> sw[256..511]
      }
      size_t cb = (size_t)(b*4 + (st>>2))*6144 + (st&3)*1536 + h*512;
      *(short8*)&catg[cb + lane*8] = ((const short8*)sw)[lane];
    }
  }
}

// ---------------------------------------------------------------------------
// kB: fused tail, WAVE-AUTONOMOUS: each wave owns 16 rows end-to-end.
// ---------------------------------------------------------------------------
__global__ __launch_bounds__(256) void kB_tail(
    const unsigned short* __restrict__ catg, const unsigned short* __restrict__ xskip,
    const unsigned short* __restrict__ w1f, const float* __restrict__ b1,
    const unsigned short* __restrict__ w2f, const float* __restrict__ b2,
    const unsigned short* __restrict__ p1f, const float* __restrict__ p1b,
    const unsigned short* __restrict__ p2f, const float* __restrict__ pb2,
    const unsigned short* __restrict__ p3f, const float* __restrict__ pb3,
    const unsigned short* __restrict__ p4f, const float* __restrict__ pb4,
    const float* __restrict__ outw, float* __restrict__ part)
{
  __shared__ unsigned short scr[4][1024];  // per-wave 2 KB
  __shared__ float red[4];
  const int tid = threadIdx.x, lane = tid&63, wv = tid>>6;
  const int c15 = lane&15, rg = lane>>4;
  const int bid = blockIdx.x, b = bid>>2, sg = bid&3;
  unsigned short* sw = scr[wv];
  const short8* w1 = (const short8*)w1f;
  const short8* w2 = (const short8*)w2f;
  const short8* q1 = (const short8*)p1f;
  const short8* q2 = (const short8*)p2f;
  const short8* q3 = (const short8*)p3f;
  const short8* q4 = (const short8*)p4f;
  const f32x4 z4 = {0.f,0.f,0.f,0.f};
  const int slot_base = (c15>>3)*128 + rg*32 + (c15&7);

  const short8* cg = (const short8*)(catg + (size_t)bid*6144 + wv*1536);
  short8 ac0 = cg[lane], ac1 = cg[64+lane], ac2 = cg[128+lane];

  short8 a0, a1;
  {  // mhp G1 (12 MFMA) -> scratch -> a0,a1
#pragma unroll
    for(int nt=0; nt<4; ++nt){
      f32x4 acc = MFMA(ac0, w1[(0*4+nt)*64+lane], z4);
      acc = MFMA(ac1, w1[(1*4+nt)*64+lane], acc);
      acc = MFMA(ac2, w1[(2*4+nt)*64+lane], acc);
      float bb = b1[nt*16+c15];
#pragma unroll
      for(int r=0;r<4;++r)
        sw[ (nt>>1)*512 + (nt&1)*256 + slot_base + r*8 ] = f2b(acc[r]+bb);
    }
    a0 = ((const short8*)sw)[lane]; a1 = ((const short8*)sw)[64+lane];
  }
  f32x4 xs2[4];
  const unsigned short* xr = xskip + (size_t)(b*256 + sg*64 + wv*16)*64;
  {  // mhp G2 + residual -> xs2 regs
#pragma unroll
    for(int nt=0; nt<4; ++nt){
      f32x4 acc = MFMA(a0, w2[(0*4+nt)*64+lane], z4);
      acc = MFMA(a1, w2[(1*4+nt)*64+lane], acc);
      float bb = b2[nt*16+c15];
#pragma unroll
      for(int r=0;r<4;++r)
        xs2[nt][r] = acc[r] + bb + b2f(xr[(rg*4+r)*64 + nt*16 + c15]);
    }
  }
  {  // LN (in-wave) -> z2 -> scratch -> a0,a1
#pragma unroll
    for(int r=0;r<4;++r){
      float s = xs2[0][r]+xs2[1][r]+xs2[2][r]+xs2[3][r];
      float q = xs2[0][r]*xs2[0][r]+xs2[1][r]*xs2[1][r]
              + xs2[2][r]*xs2[2][r]+xs2[3][r]*xs2[3][r];
      s += __shfl_xor(s,1); s += __shfl_xor(s,2); s += __shfl_xor(s,4); s += __shfl_xor(s,8);
      q += __shfl_xor(q,1); q += __shfl_xor(q,2); q += __shfl_xor(q,4); q += __shfl_xor(q,8);
      float mean = s*(1.f/64.f);
      float rstd = rsqrtf(q*(1.f/64.f) - mean*mean + 1e-5f);
#pragma unroll
      for(int nt=0;nt<4;++nt)
        sw[ (nt>>1)*512 + (nt&1)*256 + slot_base + r*8 ] = f2b((xs2[nt][r]-mean)*rstd);
    }
    a0 = ((const short8*)sw)[lane]; a1 = ((const short8*)sw)[64+lane];
  }
  {  // mlp G1 (folded)
#pragma unroll
    for(int nt=0; nt<4; ++nt){
      f32x4 acc = MFMA(a0, q1[(0*4+nt)*64+lane], z4);
      acc = MFMA(a1, q1[(1*4+nt)*64+lane], acc);
      float bb = p1b[nt*16+c15];
#pragma unroll
      for(int r=0;r<4;++r)
        sw[ (nt>>1)*512 + (nt&1)*256 + slot_base + r*8 ] = f2b(acc[r]+bb);
    }
    a0 = ((const short8*)sw)[lane]; a1 = ((const short8*)sw)[64+lane];
  }
  {  // mlp G2 + exact gelu
#pragma unroll
    for(int nt=0; nt<4; ++nt){
      f32x4 acc = MFMA(a0, q2[(0*4+nt)*64+lane], z4);
      acc = MFMA(a1, q2[(1*4+nt)*64+lane], acc);
      float bb = pb2[nt*16+c15];
#pragma unroll
      for(int r=0;r<4;++r){
        float v = acc[r] + bb;
        v = 0.5f*v*(1.f + erff(v*0.70710678118654752440f));
        sw[ (nt>>1)*512 + (nt&1)*256 + slot_base + r*8 ] = f2b(v);
      }
    }
    a0 = ((const short8*)sw)[lane]; a1 = ((const short8*)sw)[64+lane];
  }
  {  // mlp G3
#pragma unroll
    for(int nt=0; nt<4; ++nt){
      f32x4 acc = MFMA(a0, q3[(0*4+nt)*64+lane], z4);
      acc = MFMA(a1, q3[(1*4+nt)*64+lane], acc);
      float bb = pb3[nt*16+c15];
#pragma unroll
      for(int r=0;r<4;++r)
        sw[ (nt>>1)*512 + (nt&1)*256 + slot_base + r*8 ] = f2b(acc[r]+bb);
    }
    a0 = ((const short8*)sw)[lane]; a1 = ((const short8*)sw)[64+lane];
  }
  float partial = 0.f;
  {  // mlp G4 + residual + out_W dot
    const float* ow = outw + (sg*64 + wv*16)*64;
#pragma unroll
    for(int nt=0; nt<4; ++nt){
      f32x4 acc = MFMA(a0, q4[(0*4+nt)*64+lane], z4);
      acc = MFMA(a1, q4[(1*4+nt)*64+lane], acc);
      float bb = pb4[nt*16+c15];
#pragma unroll
      for(int r=0;r<4;++r){
        float v = acc[r] + bb + xs2[nt][r];
        partial += v * ow[(rg*4+r)*64 + nt*16 + c15];
      }
    }
  }
  partial += __shfl_xor(partial,1); partial += __shfl_xor(partial,2);
  partial += __shfl_xor(partial,4); partial += __shfl_xor(partial,8);
  partial += __shfl_xor(partial,16); partial += __shfl_xor(partial,32);
  if(lane==0) red[wv] = partial;
  __syncthreads();
  if(tid==0) part[bid] = red[0]+red[1]+red[2]+red[3];
}

__global__ void k5_out(const float* __restrict__ part, const float* __restrict__ outb,
                       float* __restrict__ out){
  int b = threadIdx.x;
  out[b] = part[b*4] + part[b*4+1] + part[b*4+2] + part[b*4+3] + outb[0];
}

// ---------------------------------------------------------------------------
extern "C" void kernel_launch(void* const* d_in, const int* in_sizes, int n_in,
                              void* d_out, int out_size, void* d_ws, size_t ws_size,
                              hipStream_t stream)
{
  const float* x    = (const float*)d_in[0];
  const float* ln1s = (const float*)d_in[1];
  const float* ln1b = (const float*)d_in[2];
  const float* inW  = (const float*)d_in[3];
  const float* inb  = (const float*)d_in[4];
  const float* ln2s = (const float*)d_in[5];
  const float* ln2b = (const float*)d_in[6];
  const float* mss  = (const float*)d_in[7];
  const float* msb  = (const float*)d_in[8];
  const float* Wq   = (const float*)d_in[9];
  const float* bq   = (const float*)d_in[10];
  const float* Wk   = (const float*)d_in[11];
  const float* bk   = (const float*)d_in[12];
  const float* Wv   = (const float*)d_in[13];
  const float* bv   = (const float*)d_in[14];
  const float* mhW1 = (const float*)d_in[15];
  const float* mhb1 = (const float*)d_in[16];
  const float* mhW2 = (const float*)d_in[17];
  const float* mhb2 = (const float*)d_in[18];
  const float* mls  = (const float*)d_in[19];
  const float* mlb  = (const float*)d_in[20];
  const float* mW1  = (const float*)d_in[21];
  const float* mb1  = (const float*)d_in[22];
  const float* mW2  = (const float*)d_in[23];
  const float* mb2  = (const float*)d_in[24];
  const float* mW3  = (const float*)d_in[25];
  const float* mb3  = (const float*)d_in[26];
  const float* mW4  = (const float*)d_in[27];
  const float* mb4  = (const float*)d_in[28];
  const float* outW = (const float*)d_in[29];
  const float* outb = (const float*)d_in[30];
  (void)in_sizes; (void)n_in; (void)out_size;

  // workspace layout (bytes)
  char* ws = (char*)d_ws;
  unsigned short* xskip = (unsigned short*)(ws + 0);          //  8,388,608
  unsigned short* catg  = (unsigned short*)(ws + 8388608);    // 12,582,912
  unsigned short* wsw   = (unsigned short*)(ws + 20971520);   //    188,416
  unsigned short* zf    = (unsigned short*)(ws + 21159936);   //  8,388,608
  float*          qkvb  = (float*)         (ws + 29548544);   //      1,152
  float*          mlpb1 = (float*)         (ws + 29549696);   //        256
  float*          part  = (float*)         (ws + 29549952);   //      4,096
  if(ws_size < 29554048u) return;

  float* out = (float*)d_out;

  kprep<<<dim3(192), dim3(256), 0, stream>>>(inW, wsw);
  k1_patch<<<dim3(198 + 4096), dim3(256), 0, stream>>>(x, ln1s, ln1b, wsw, inb,
      ln2s, ln2b, xskip, zf,
      inW, Wq, Wk, Wv, mhW1, mhW2, mW1, mW2, mW3, mW4,
      mss, mls, msb, bq, bk, bv, mlb, mb1, qkvb, mlpb1);
  kA_attn<<<dim3(768), dim3(256), 0, stream>>>(zf, wsw, qkvb, catg);
  kB_tail<<<dim3(1024), dim3(256), 0, stream>>>(catg, xskip,
      wsw + 67584, mhb1, wsw + 73728, mhb2,
      wsw + 77824, mlpb1, wsw + 81920, mb2, wsw + 86016, mb3, wsw + 90112, mb4,
      outW, part);
  k5_out<<<dim3(1), dim3(256), 0, stream>>>(part, outb, out);
}

// Round 15
// 91.012 us; speedup vs baseline: 1.0135x; 1.0135x over previous
//
#include <hip/hip_runtime.h>
#include <math.h>

typedef __attribute__((ext_vector_type(8))) short short8;
typedef __attribute__((ext_vector_type(4))) short short4v;
typedef __attribute__((ext_vector_type(4))) float f32x4;
typedef __attribute__((ext_vector_type(2))) float f32x2;

#define DEV static __device__ __forceinline__

DEV unsigned short f2b(float f){            // fp32 -> bf16 (RNE)
  union{float f; unsigned u;} x; x.f = f;
  unsigned r = (x.u + 0x7fffu + ((x.u>>16)&1u))>>16;
  return (unsigned short)r;
}
DEV float b2f(unsigned short u){            // bf16 -> fp32
  union{unsigned u; float f;} x; x.u = ((unsigned)u)<<16; return x.f;
}

#define MFMA(a,b,c) __builtin_amdgcn_mfma_f32_16x16x32_bf16((a),(b),(c),0,0,0)

// ---------------------------------------------------------------------------
// Weight-prep: ids [0,94208) -> bf16 B-frag order (LN-affine folded);
// [94208,98816): qkv bias folds, 16 lanes per element (shfl tree reduce);
// [98816,99840): mlp b1 fold, 16 lanes per element.
// ---------------------------------------------------------------------------
DEV void prep_one(int id,
    const float* inW, const float* Wq, const float* Wk, const float* Wv,
    const float* m1, const float* m2,
    const float* p1, const float* p2, const float* p3, const float* p4,
    const float* mss, const float* mls, const float* msb,
    const float* bq, const float* bk, const float* bv,
    const float* mlb, const float* mb1,
    unsigned short* wsw, float* qkvb, float* mlpb1)
{
  if(id < 94208){
    const float* src; int NT, base; int harg = -1, w1flag = 0;
    if      (id < 49152){ src=inW; NT=4; base=0; }
    else if (id < 67584){ int r=id-49152; int slab=r>>11; int h=slab/3, m=slab-h*3;
                          src=(m==0?Wq:(m==1?Wk:Wv))+h*2048; NT=2; base=49152+slab*2048; harg=h; }
    else if (id < 73728){ src=m1; NT=4; base=67584; }
    else if (id < 77824){ src=m2; NT=4; base=73728; }
    else if (id < 81920){ src=p1; NT=4; base=77824; w1flag=1; }
    else if (id < 86016){ src=p2; NT=4; base=81920; }
    else if (id < 90112){ src=p3; NT=4; base=86016; }
    else                { src=p4; NT=4; base=90112; }
    int o = id - base;
    int j = o&7, l = (o>>3)&63, rest = o>>9;
    int nt = rest % NT, kc = rest / NT;
    int k = kc*32 + ((l>>4)<<3) + j;
    int n = nt*16 + (l&15);
    float scale = 1.f;
    if(harg >= 0) scale = mss[harg*64 + k];
    if(w1flag)    scale = mls[k];
    wsw[id] = f2b(src[k*(NT*16) + n] * scale);
  } else if(id < 98816){
    int o16 = id - 94208;                   // 4608 = 288 elems * 16 lanes
    int elem = o16 >> 4, part = o16 & 15;
    int h = elem/96, m = (elem - h*96)/32, e = elem&31;
    const float* W  = (m==0?Wq:(m==1?Wk:Wv)) + h*2048;
    const float* bb = (m==0?bq:(m==1?bk:bv));
    float s = 0.f;
#pragma unroll
    for(int u=0; u<4; ++u){
      int l = part*4 + u;
      s += msb[h*64+l]*W[l*32+e];
    }
    s += __shfl_xor(s,1); s += __shfl_xor(s,2);
    s += __shfl_xor(s,4); s += __shfl_xor(s,8);
    if(part==0) qkvb[elem] = s + bb[h*32+e];
  } else if(id < 99840){
    int o16 = id - 98816;                   // 1024 = 64 elems * 16 lanes
    int n = o16 >> 4, part = o16 & 15;
    float s = 0.f;
#pragma unroll
    for(int u=0; u<4; ++u){
      int l = part*4 + u;
      s += mlb[l]*p1[l*64+n];
    }
    s += __shfl_xor(s,1); s += __shfl_xor(s,2);
    s += __shfl_xor(s,4); s += __shfl_xor(s,8);
    if(part==0) mlpb1[n] = s + mb1[n];
  }
}

// kprep: in_W frags (needed by k1). 192 blocks.
__global__ __launch_bounds__(256) void kprep(
    const float* __restrict__ inW, unsigned short* __restrict__ wsw)
{
  int id = blockIdx.x*256 + threadIdx.x;   // < 49152
  int o = id;
  int j = o&7, l = (o>>3)&63, rest = o>>9;
  int nt = rest & 3, kc = rest >> 2;
  int k = kc*32 + ((l>>4)<<3) + j;
  int n = nt*16 + (l&15);
  wsw[id] = f2b(inW[k*64 + n]);
}

// ---------------------------------------------------------------------------
// k1: blocks [0,198): weight prep. blocks [198,4294): patchify + LN(768) +
// GEMM(768->64) + bias + LN(64) -> xskip (bf16) + z (bf16, kA A-frag order).
// ---------------------------------------------------------------------------
__global__ __launch_bounds__(256) void k1_patch(
    const float* __restrict__ x,
    const float* __restrict__ ln1s, const float* __restrict__ ln1b,
    unsigned short* __restrict__ wsw, const float* __restrict__ inb,
    const float* __restrict__ ln2s, const float* __restrict__ ln2b,
    unsigned short* __restrict__ xskip, unsigned short* __restrict__ zf,
    const float* __restrict__ inW,
    const float* __restrict__ Wq, const float* __restrict__ Wk,
    const float* __restrict__ Wv,
    const float* __restrict__ m1, const float* __restrict__ m2,
    const float* __restrict__ p1, const float* __restrict__ p2,
    const float* __restrict__ p3, const float* __restrict__ p4,
    const float* __restrict__ mss, const float* __restrict__ mls,
    const float* __restrict__ msb,
    const float* __restrict__ bq, const float* __restrict__ bk,
    const float* __restrict__ bv,
    const float* __restrict__ mlb, const float* __restrict__ mb1,
    float* __restrict__ qkvb, float* __restrict__ mlpb1)
{
  const int tid = threadIdx.x;
  const int bp = blockIdx.x;
  if(bp < 198){   // weight-prep first
    int id = 49152 + bp*256 + tid;
    if(id < 99840)
      prep_one(id, inW, Wq, Wk, Wv, m1, m2, p1, p2, p3, p4,
               mss, mls, msb, bq, bk, bv, mlb, mb1, wsw, qkvb, mlpb1);
    return;
  }
  const int bp2 = bp - 198;
  __shared__ unsigned short Tf[24*64*8];
  __shared__ float Cbuf[16][68];
  __shared__ float wstat[4][16][2];
  const int lane = tid & 63, wv = tid >> 6;
  const int b = bp2 >> 4, p0 = bp2 & 15;
  const int a = lane & 3;

  const float* xb = x + (size_t)b * (3*256*256);
  f32x4 rv[12];
  float sum[4] = {0.f,0.f,0.f,0.f}, ssq[4] = {0.f,0.f,0.f,0.f};
#pragma unroll
  for(int it=0; it<12; ++it){
    int rr = it*4 + wv;            // row 0..47 (wave-striped)
    int c = rr >> 4, i = rr & 15;
    rv[it] = *(const f32x4*)&xb[(size_t)(c*256 + i*16 + p0)*256 + lane*4];
#pragma unroll
    for(int u=0; u<4; ++u){ float v = rv[it][u]; sum[u] += v; ssq[u] += v*v; }
  }
#pragma unroll
  for(int u=0; u<4; ++u){
    sum[u] += __shfl_xor(sum[u],4);  ssq[u] += __shfl_xor(ssq[u],4);
    sum[u] += __shfl_xor(sum[u],8);  ssq[u] += __shfl_xor(ssq[u],8);
    sum[u] += __shfl_xor(sum[u],16); ssq[u] += __shfl_xor(ssq[u],16);
    sum[u] += __shfl_xor(sum[u],32); ssq[u] += __shfl_xor(ssq[u],32);
  }
  if(lane < 4){
#pragma unroll
    for(int u=0; u<4; ++u){
      wstat[wv][lane*4+u][0] = sum[u];
      wstat[wv][lane*4+u][1] = ssq[u];
    }
  }
  __syncthreads();
  float mean[4], rstd[4];
#pragma unroll
  for(int u=0; u<4; ++u){
    int pv = a*4 + u;
    float ts = wstat[0][pv][0]+wstat[1][pv][0]+wstat[2][pv][0]+wstat[3][pv][0];
    float tq = wstat[0][pv][1]+wstat[1][pv][1]+wstat[2][pv][1]+wstat[3][pv][1];
    mean[u] = ts * (1.f/768.f);
    rstd[u] = rsqrtf(tq*(1.f/768.f) - mean[u]*mean[u] + 1e-5f);
  }
#pragma unroll
  for(int it=0; it<12; ++it){
    int rr = it*4 + wv;
    int c = rr >> 4, i = rr & 15, j = lane >> 2;
    int d = c*256 + i*16 + j;
    float ls = ln1s[d], lb = ln1b[d];
    int tb = ((d>>5)*64 + ((d&31)>>3)*16)*8 + (d&7);
#pragma unroll
    for(int u=0; u<4; ++u){
      float xv = (rv[it][u]-mean[u])*rstd[u]*ls + lb;
      Tf[ tb + (a*4+u)*8 ] = f2b(xv);
    }
  }
  __syncthreads();

  f32x4 acc = {0.f,0.f,0.f,0.f};
  const short8* wf = (const short8*)wsw;
#pragma unroll
  for(int kc=0; kc<24; ++kc){
    short8 aa = *(const short8*)&Tf[(kc*64 + lane)*8];
    short8 bb = wf[(kc*4 + wv)*64 + lane];
    acc = MFMA(aa, bb, acc);
  }
  const int c15 = lane & 15, rg = lane >> 4;
  float bias = inb[wv*16 + c15];
#pragma unroll
  for(int r=0; r<4; ++r) Cbuf[rg*4+r][wv*16+c15] = acc[r] + bias;
  __syncthreads();

  {
    int row = tid >> 4, cq = (tid & 15) * 4;
    float v0=Cbuf[row][cq+0], v1=Cbuf[row][cq+1], v2=Cbuf[row][cq+2], v3=Cbuf[row][cq+3];
    float s = v0+v1+v2+v3;
    float q = v0*v0+v1*v1+v2*v2+v3*v3;
    s += __shfl_xor(s,1); s += __shfl_xor(s,2); s += __shfl_xor(s,4); s += __shfl_xor(s,8);
    q += __shfl_xor(q,1); q += __shfl_xor(q,2); q += __shfl_xor(q,4); q += __shfl_xor(q,8);
    float m2  = s*(1.f/64.f);
    float rs2 = rsqrtf(q*(1.f/64.f) - m2*m2 + 1e-5f);
    f32x4 o;
    o[0] = (v0-m2)*rs2*ln2s[cq+0] + ln2b[cq+0];
    o[1] = (v1-m2)*rs2*ln2s[cq+1] + ln2b[cq+1];
    o[2] = (v2-m2)*rs2*ln2s[cq+2] + ln2b[cq+2];
    o[3] = (v3-m2)*rs2*ln2s[cq+3] + ln2b[cq+3];
    int grow = b*256 + p0*16 + row;
    short4v xb4;
    xb4[0]=(short)f2b(o[0]); xb4[1]=(short)f2b(o[1]);
    xb4[2]=(short)f2b(o[2]); xb4[3]=(short)f2b(o[3]);
    *(short4v*)&xskip[ (size_t)grow*64 + cq ] = xb4;
    // second LN stats (all 16 lanes get totals via butterfly)
    float s2 = o[0]+o[1]+o[2]+o[3];
    float q2 = o[0]*o[0]+o[1]*o[1]+o[2]*o[2]+o[3]*o[3];
    s2 += __shfl_xor(s2,1); s2 += __shfl_xor(s2,2); s2 += __shfl_xor(s2,4); s2 += __shfl_xor(s2,8);
    q2 += __shfl_xor(q2,1); q2 += __shfl_xor(q2,2); q2 += __shfl_xor(q2,4); q2 += __shfl_xor(q2,8);
    float mm  = s2*(1.f/64.f);
    float rr2 = rsqrtf(q2*(1.f/64.f) - mm*mm + 1e-5f);
    short4v zz;
    zz[0] = (short)f2b((o[0]-mm)*rr2);
    zz[1] = (short)f2b((o[1]-mm)*rr2);
    zz[2] = (short)f2b((o[2]-mm)*rr2);
    zz[3] = (short)f2b((o[3]-mm)*rr2);
    int fi = (p0*2 + (cq>>5))*512 + ((cq&31)>>3)*128 + row*8 + (cq&7);
    *(short4v*)&zf[ (size_t)b*16384 + fi ] = zz;
  }
}

// ---------------------------------------------------------------------------
// kA: fused attention per (b,h). A-frags (z) loaded directly from global
// (coalesced 16B/lane); QKV -> Q regs / K,V LDS; QK^T, in-register softmax
// (normalization DEFERRED to output), P staged per-kc via per-wave scratch,
// PV; O staged through scratch -> contiguous short8 catg stores.
// ---------------------------------------------------------------------------
__global__ __launch_bounds__(256) void kA_attn(
    const unsigned short* __restrict__ zf,
    const unsigned short* __restrict__ wsw, const float* __restrict__ qkvb,
    unsigned short* __restrict__ catg)
{
  __shared__ unsigned short Kf[8192];      // 16 KB
  __shared__ unsigned short Vf[8192];      // 16 KB
  __shared__ unsigned short scr[4][1024];  //  8 KB (per-wave 2 KB)
  const int tid = threadIdx.x, lane = tid&63, wv = tid>>6;
  const int c15 = lane&15, rg = lane>>4;
  const int id = blockIdx.x, b = id/3, h = id - b*3;
  const short8* zg = (const short8*)(zf + (size_t)b*16384);
  const short8* wf = ((const short8*)(wsw + 49152)) + h*3*256;
  unsigned short* sw = scr[wv];
  float be[6];
#pragma unroll
  for(int i=0;i<6;++i) be[i] = qkvb[(h*3 + (i>>1))*32 + (i&1)*16 + c15];

  short8 aq[4];                            // Q A-frags, one per st
#pragma unroll
  for(int si=0; si<4; ++si){
    const int st = wv + si*4;
    short8 a0 = zg[(st*2+0)*64 + lane];
    short8 a1 = zg[(st*2+1)*64 + lane];
#pragma unroll
    for(int mat=0; mat<3; ++mat){
#pragma unroll
      for(int et=0; et<2; ++et){
        f32x4 acc = {0.f,0.f,0.f,0.f};
        acc = MFMA(a0, wf[mat*256 + et*64 + lane], acc);
        acc = MFMA(a1, wf[mat*256 + (2+et)*64 + lane], acc);
        float bias = be[mat*2+et];
#pragma unroll
        for(int r=0;r<4;++r){
          unsigned short val = f2b(acc[r] + bias);
          int s15 = rg*4 + r;
          if(mat==0){
            sw[ ((et*2 + (c15>>3))*16 + s15)*8 + (c15&7) ] = val;
          } else if(mat==1){
            Kf[ (st*64 + (et*2 + (c15>>3))*16 + s15)*8 + (c15&7) ] = val;
          } else {
            int s = st*16 + s15;
            Vf[ (((s>>5)*2 + et)*64 + ((s&31)>>3)*16 + c15)*8 + (s&7) ] = val;
          }
        }
      }
      if(mat==0) aq[si] = ((const short8*)sw)[lane];   // wave-local readback
    }
  }
  __syncthreads();

  const f32x4 z4 = {0.f,0.f,0.f,0.f};
#pragma unroll
  for(int si=0; si<4; ++si){
    const int st = wv + si*4;
    f32x4 sc[16];
#pragma unroll
    for(int tt=0; tt<16; ++tt) sc[tt] = MFMA(aq[si], ((const short8*)Kf)[tt*64 + lane], z4);
    float mx[4], sm[4];
#pragma unroll
    for(int r=0; r<4; ++r){
      float m = sc[0][r];
#pragma unroll
      for(int tt=1; tt<16; ++tt) m = fmaxf(m, sc[tt][r]);
      m = fmaxf(m, __shfl_xor(m,1)); m = fmaxf(m, __shfl_xor(m,2));
      m = fmaxf(m, __shfl_xor(m,4)); m = fmaxf(m, __shfl_xor(m,8));
      mx[r] = m; sm[r] = 0.f;
    }
#pragma unroll
    for(int tt=0; tt<16; ++tt)
#pragma unroll
      for(int r=0; r<4; ++r){
        float e = __expf(sc[tt][r] - mx[r]);
        sc[tt][r] = e; sm[r] += e;
      }
#pragma unroll
    for(int r=0; r<4; ++r){
      float s = sm[r];
      s += __shfl_xor(s,1); s += __shfl_xor(s,2); s += __shfl_xor(s,4); s += __shfl_xor(s,8);
      sm[r] = 1.f / s;
    }
    f32x4 o0 = z4, o1 = z4;
#pragma unroll
    for(int kc=0; kc<8; ++kc){
#pragma unroll
      for(int t2=0; t2<2; ++t2){
        int tt = kc*2 + t2;
        int tbr = t2*16 + c15;
#pragma unroll
        for(int r=0; r<4; ++r)
          sw[ (((tbr>>3)*16 + rg*4 + r)<<3) + (tbr&7) ] = f2b(sc[tt][r]);  // raw exp
      }
      short8 pa = ((const short8*)sw)[lane];
      o0 = MFMA(pa, ((const short8*)Vf)[(kc*2+0)*64 + lane], o0);
      o1 = MFMA(pa, ((const short8*)Vf)[(kc*2+1)*64 + lane], o1);
    }
    {  // deferred normalization + stage via scratch -> contiguous stores
      int fo = (c15>>3)*128 + (c15&7);
#pragma unroll
      for(int r=0; r<4; ++r){
        int q8 = (rg*4 + r)*8;
        sw[ fo + q8 ]       = f2b(o0[r]*sm[r]);   // et0 tile -> sw[0..255]
        sw[ 256 + fo + q8 ] = f2b(o1[r]*sm[r]);   // et1 tile -> sw[256..511]
      }
      size_t cb = (size_t)(b*4 + (st>>2))*6144 + (st&3)*1536 + h*512;
      *(short8*)&catg[cb + lane*8] = ((const short8*)sw)[lane];
    }
  }
}

// ---------------------------------------------------------------------------
// kB: fused tail, WAVE-AUTONOMOUS: each wave owns 16 rows end-to-end.
// ---------------------------------------------------------------------------
__global__ __launch_bounds__(256) void kB_tail(
    const unsigned short* __restrict__ catg, const unsigned short* __restrict__ xskip,
    const unsigned short* __restrict__ w1f, const float* __restrict__ b1,
    const unsigned short* __restrict__ w2f, const float* __restrict__ b2,
    const unsigned short* __restrict__ p1f, const float* __restrict__ p1b,
    const unsigned short* __restrict__ p2f, const float* __restrict__ pb2,
    const unsigned short* __restrict__ p3f, const float* __restrict__ pb3,
    const unsigned short* __restrict__ p4f, const float* __restrict__ pb4,
    const float* __restrict__ outw, float* __restrict__ part)
{
  __shared__ unsigned short scr[4][1024];  // per-wave 2 KB
  __shared__ float red[4];
  const int tid = threadIdx.x, lane = tid&63, wv = tid>>6;
  const int c15 = lane&15, rg = lane>>4;
  const int bid = blockIdx.x, b = bid>>2, sg = bid&3;
  unsigned short* sw = scr[wv];
  const short8* w1 = (const short8*)w1f;
  const short8* w2 = (const short8*)w2f;
  const short8* q1 = (const short8*)p1f;
  const short8* q2 = (const short8*)p2f;
  const short8* q3 = (const short8*)p3f;
  const short8* q4 = (const short8*)p4f;
  const f32x4 z4 = {0.f,0.f,0.f,0.f};
  const int slot_base = (c15>>3)*128 + rg*32 + (c15&7);

  const short8* cg = (const short8*)(catg + (size_t)bid*6144 + wv*1536);
  short8 ac0 = cg[lane], ac1 = cg[64+lane], ac2 = cg[128+lane];

  short8 a0, a1;
  {  // mhp G1 (12 MFMA) -> scratch -> a0,a1
#pragma unroll
    for(int nt=0; nt<4; ++nt){
      f32x4 acc = MFMA(ac0, w1[(0*4+nt)*64+lane], z4);
      acc = MFMA(ac1, w1[(1*4+nt)*64+lane], acc);
      acc = MFMA(ac2, w1[(2*4+nt)*64+lane], acc);
      float bb = b1[nt*16+c15];
#pragma unroll
      for(int r=0;r<4;++r)
        sw[ (nt>>1)*512 + (nt&1)*256 + slot_base + r*8 ] = f2b(acc[r]+bb);
    }
    a0 = ((const short8*)sw)[lane]; a1 = ((const short8*)sw)[64+lane];
  }
  f32x4 xs2[4];
  const unsigned short* xr = xskip + (size_t)(b*256 + sg*64 + wv*16)*64;
  {  // mhp G2 + residual -> xs2 regs
#pragma unroll
    for(int nt=0; nt<4; ++nt){
      f32x4 acc = MFMA(a0, w2[(0*4+nt)*64+lane], z4);
      acc = MFMA(a1, w2[(1*4+nt)*64+lane], acc);
      float bb = b2[nt*16+c15];
#pragma unroll
      for(int r=0;r<4;++r)
        xs2[nt][r] = acc[r] + bb + b2f(xr[(rg*4+r)*64 + nt*16 + c15]);
    }
  }
  {  // LN (in-wave) -> z2 -> scratch -> a0,a1
#pragma unroll
    for(int r=0;r<4;++r){
      float s = xs2[0][r]+xs2[1][r]+xs2[2][r]+xs2[3][r];
      float q = xs2[0][r]*xs2[0][r]+xs2[1][r]*xs2[1][r]
              + xs2[2][r]*xs2[2][r]+xs2[3][r]*xs2[3][r];
      s += __shfl_xor(s,1); s += __shfl_xor(s,2); s += __shfl_xor(s,4); s += __shfl_xor(s,8);
      q += __shfl_xor(q,1); q += __shfl_xor(q,2); q += __shfl_xor(q,4); q += __shfl_xor(q,8);
      float mean = s*(1.f/64.f);
      float rstd = rsqrtf(q*(1.f/64.f) - mean*mean + 1e-5f);
#pragma unroll
      for(int nt=0;nt<4;++nt)
        sw[ (nt>>1)*512 + (nt&1)*256 + slot_base + r*8 ] = f2b((xs2[nt][r]-mean)*rstd);
    }
    a0 = ((const short8*)sw)[lane]; a1 = ((const short8*)sw)[64+lane];
  }
  {  // mlp G1 (folded)
#pragma unroll
    for(int nt=0; nt<4; ++nt){
      f32x4 acc = MFMA(a0, q1[(0*4+nt)*64+lane], z4);
      acc = MFMA(a1, q1[(1*4+nt)*64+lane], acc);
      float bb = p1b[nt*16+c15];
#pragma unroll
      for(int r=0;r<4;++r)
        sw[ (nt>>1)*512 + (nt&1)*256 + slot_base + r*8 ] = f2b(acc[r]+bb);
    }
    a0 = ((const short8*)sw)[lane]; a1 = ((const short8*)sw)[64+lane];
  }
  {  // mlp G2 + exact gelu
#pragma unroll
    for(int nt=0; nt<4; ++nt){
      f32x4 acc = MFMA(a0, q2[(0*4+nt)*64+lane], z4);
      acc = MFMA(a1, q2[(1*4+nt)*64+lane], acc);
      float bb = pb2[nt*16+c15];
#pragma unroll
      for(int r=0;r<4;++r){
        float v = acc[r] + bb;
        v = 0.5f*v*(1.f + erff(v*0.70710678118654752440f));
        sw[ (nt>>1)*512 + (nt&1)*256 + slot_base + r*8 ] = f2b(v);
      }
    }
    a0 = ((const short8*)sw)[lane]; a1 = ((const short8*)sw)[64+lane];
  }
  {  // mlp G3
#pragma unroll
    for(int nt=0; nt<4; ++nt){
      f32x4 acc = MFMA(a0, q3[(0*4+nt)*64+lane], z4);
      acc = MFMA(a1, q3[(1*4+nt)*64+lane], acc);
      float bb = pb3[nt*16+c15];
#pragma unroll
      for(int r=0;r<4;++r)
        sw[ (nt>>1)*512 + (nt&1)*256 + slot_base + r*8 ] = f2b(acc[r]+bb);
    }
    a0 = ((const short8*)sw)[lane]; a1 = ((const short8*)sw)[64+lane];
  }
  float partial = 0.f;
  {  // mlp G4 + residual + out_W dot
    const float* ow = outw + (sg*64 + wv*16)*64;
#pragma unroll
    for(int nt=0; nt<4; ++nt){
      f32x4 acc = MFMA(a0, q4[(0*4+nt)*64+lane], z4);
      acc = MFMA(a1, q4[(1*4+nt)*64+lane], acc);
      float bb = pb4[nt*16+c15];
#pragma unroll
      for(int r=0;r<4;++r){
        float v = acc[r] + bb + xs2[nt][r];
        partial += v * ow[(rg*4+r)*64 + nt*16 + c15];
      }
    }
  }
  partial += __shfl_xor(partial,1); partial += __shfl_xor(partial,2);
  partial += __shfl_xor(partial,4); partial += __shfl_xor(partial,8);
  partial += __shfl_xor(partial,16); partial += __shfl_xor(partial,32);
  if(lane==0) red[wv] = partial;
  __syncthreads();
  if(tid==0) part[bid] = red[0]+red[1]+red[2]+red[3];
}

__global__ void k5_out(const float* __restrict__ part, const float* __restrict__ outb,
                       float* __restrict__ out){
  int b = threadIdx.x;
  out[b] = part[b*4] + part[b*4+1] + part[b*4+2] + part[b*4+3] + outb[0];
}

// ---------------------------------------------------------------------------
extern "C" void kernel_launch(void* const* d_in, const int* in_sizes, int n_in,
                              void* d_out, int out_size, void* d_ws, size_t ws_size,
                              hipStream_t stream)
{
  const float* x    = (const float*)d_in[0];
  const float* ln1s = (const float*)d_in[1];
  const float* ln1b = (const float*)d_in[2];
  const float* inW  = (const float*)d_in[3];
  const float* inb  = (const float*)d_in[4];
  const float* ln2s = (const float*)d_in[5];
  const float* ln2b = (const float*)d_in[6];
  const float* mss  = (const float*)d_in[7];
  const float* msb  = (const float*)d_in[8];
  const float* Wq   = (const float*)d_in[9];
  const float* bq   = (const float*)d_in[10];
  const float* Wk   = (const float*)d_in[11];
  const float* bk   = (const float*)d_in[12];
  const float* Wv   = (const float*)d_in[13];
  const float* bv   = (const float*)d_in[14];
  const float* mhW1 = (const float*)d_in[15];
  const float* mhb1 = (const float*)d_in[16];
  const float* mhW2 = (const float*)d_in[17];
  const float* mhb2 = (const float*)d_in[18];
  const float* mls  = (const float*)d_in[19];
  const float* mlb  = (const float*)d_in[20];
  const float* mW1  = (const float*)d_in[21];
  const float* mb1  = (const float*)d_in[22];
  const float* mW2  = (const float*)d_in[23];
  const float* mb2  = (const float*)d_in[24];
  const float* mW3  = (const float*)d_in[25];
  const float* mb3  = (const float*)d_in[26];
  const float* mW4  = (const float*)d_in[27];
  const float* mb4  = (const float*)d_in[28];
  const float* outW = (const float*)d_in[29];
  const float* outb = (const float*)d_in[30];
  (void)in_sizes; (void)n_in; (void)out_size;

  // workspace layout (bytes)
  char* ws = (char*)d_ws;
  unsigned short* xskip = (unsigned short*)(ws + 0);          //  8,388,608
  unsigned short* catg  = (unsigned short*)(ws + 8388608);    // 12,582,912
  unsigned short* wsw   = (unsigned short*)(ws + 20971520);   //    188,416
  unsigned short* zf    = (unsigned short*)(ws + 21159936);   //  8,388,608
  float*          qkvb  = (float*)         (ws + 29548544);   //      1,152
  float*          mlpb1 = (float*)         (ws + 29549696);   //        256
  float*          part  = (float*)         (ws + 29549952);   //      4,096
  if(ws_size < 29554048u) return;

  float* out = (float*)d_out;

  kprep<<<dim3(192), dim3(256), 0, stream>>>(inW, wsw);
  k1_patch<<<dim3(198 + 4096), dim3(256), 0, stream>>>(x, ln1s, ln1b, wsw, inb,
      ln2s, ln2b, xskip, zf,
      inW, Wq, Wk, Wv, mhW1, mhW2, mW1, mW2, mW3, mW4,
      mss, mls, msb, bq, bk, bv, mlb, mb1, qkvb, mlpb1);
  kA_attn<<<dim3(768), dim3(256), 0, stream>>>(zf, wsw, qkvb, catg);
  kB_tail<<<dim3(1024), dim3(256), 0, stream>>>(catg, xskip,
      wsw + 67584, mhb1, wsw + 73728, mhb2,
      wsw + 77824, mlpb1, wsw + 81920, mb2, wsw + 86016, mb3, wsw + 90112, mb4,
      outW, part);
  k5_out<<<dim3(1), dim3(256), 0, stream>>>(part, outb, out);
}